// Round 9
// baseline (123.337 us; speedup 1.0000x reference)
//
#include <hip/hip_runtime.h>
#include <hip/hip_bf16.h>
#include <stdint.h>

// DecorrLoss: x (8,4096,512) fp32, kappa scalar ->
//   grad (512,512), correlation_loss (scalar), whitening_loss (scalar)
// out layout: [0..262143] grad, [262144] corr, [262145] whit
//
// Identities:
//   corr  = sum_n (s2_n^2 - s4_n) / (N d^2)
//   whit  = sum_n (s4_n - 2 s2_n) / (N d^2) + 1/d
//   grad  = (1-k)/N * gram off-diag,  k*(gram_ii/N - 1) on diag,  gram = X^T X
//
// R9: prep de-storm. R8 showed byte-halving was neutral -> prep/gram are
// issue/latency-bound, not BW-bound. prep's 96-shfl loss reduction (8 trees x
// 2 x 6 levels) is cut to 46 via ownership-reduce, and reordered so the
// transpose stores issue BEFORE the shuffle storm (ds pipe overlaps vm pipe).
// Loss partials: one float2 per WAVE (lpart4[4096], x8 sample replication
// folded into the final scale). gram/finalize structure unchanged from R8.
// xt image, byte addr of (f,k):
//   f*32768 + (k>>6)*64 + (((k>>3)&7 ^ (f&7))*8) + (k&7)

#define D 512
#define NSAMP 32768
#define KPARTS 64
#define NTILES 10
#define NCHUNK 8          // 8 chunks of 64 samples per kpart (KC=512)
#define PREP_BLOCKS 1024
#define KPARTS_FB 32
#define KC_FB 1024
#define BK_FB 64
#define NCHUNK_FB 16

typedef __bf16 bf16x8 __attribute__((ext_vector_type(8)));
typedef float floatx4 __attribute__((ext_vector_type(4)));
typedef __attribute__((address_space(1))) const uint32_t gas_u32;
typedef __attribute__((address_space(3))) uint32_t las_u32;

__global__ __launch_bounds__(1024) void zero_kernel(float* out, int n) {
    int i = blockIdx.x * 1024 + threadIdx.x;
    if (i < n) out[i] = 0.0f;
}

// ---------- primary path ----------

// prep: 1024 blocks x 256 thr; block bb = samples [32bb, 32bb+32), kc = bb>>1,
// half h = bb&1. Wave w owns samples 8w..8w+7 (granule-local). Lane l loads
// float4s at f = 4l..4l+3 and 256+4l..+3 (coalesced 1KB/instr).
// Order: loads -> fp8 pack -> p2/p4 partials -> ds_write -> barrier ->
// global stores (vm pipe) -> ownership shuffle-reduce (ds pipe, overlapped) ->
// per-wave lpart4 write. Loss terms carry x8 lane replication (scaled out in
// finalize).
__global__ __launch_bounds__(256) void prep_kernel(const float* __restrict__ x,
                                                   uint8_t* __restrict__ xt,
                                                   float2* __restrict__ lpart4) {
    __shared__ char lds[512 * 32];  // 16 KB: [f 0..511][4 granules of 8 B]
    const int t = threadIdx.x;
    const int l = t & 63;
    const int w = t >> 6;
    const int bb = blockIdx.x;
    const int kc = bb >> 1;
    const int h = bb & 1;
    char* xtb = (char*)xt;

    const float* base = x + ((size_t)(32 * bb + 8 * w)) * D;
    float4 va[16];
#pragma unroll
    for (int r = 0; r < 8; ++r) {
        va[2 * r]     = *(const float4*)(base + (size_t)r * D + 4 * l);
        va[2 * r + 1] = *(const float4*)(base + (size_t)r * D + 256 + 4 * l);
    }

    // fp8 pack: per f (c2), granule byte j = sample j (matches A-frag k&7)
    const int pos_w = (w ^ (l & 3)) * 8;
#pragma unroll
    for (int c2 = 0; c2 < 8; ++c2) {
        float s[8];
#pragma unroll
        for (int r = 0; r < 8; ++r)
            s[r] = ((const float*)&va[2 * r + (c2 >> 2)])[c2 & 3];
        uint32_t w0 = __builtin_amdgcn_cvt_pk_fp8_f32(s[0], s[1], 0, false);
        w0 = __builtin_amdgcn_cvt_pk_fp8_f32(s[2], s[3], w0, true);
        uint32_t w1 = __builtin_amdgcn_cvt_pk_fp8_f32(s[4], s[5], 0, false);
        w1 = __builtin_amdgcn_cvt_pk_fp8_f32(s[6], s[7], w1, true);
        const int f = (c2 < 4) ? (4 * l + c2) : (256 + 4 * l + (c2 - 4));
        uint2 v;
        v.x = w0;
        v.y = w1;
        *(uint2*)(lds + f * 32 + pos_w) = v;
    }

    // per-sample partial sums (frees va)
    float p2[8], p4[8];
#pragma unroll
    for (int r = 0; r < 8; ++r) {
        float a2 = 0.f, a4 = 0.f, e;
#pragma unroll
        for (int c = 0; c < 8; ++c) {
            const float v = ((const float*)&va[2 * r])[c];
            e = v * v;
            a2 += e;
            a4 += e * e;
        }
        p2[r] = a2;
        p4[r] = a4;
    }

    __syncthreads();  // transpose image complete

    // store phase first: instr i covers f = i*64 + w*16 + (l>>2); granule
    // d = l&3; LDS pos = d ^ ((l>>4)&3); global granule G = 4h+d at
    // position G ^ (f&7) in the 64 B row.
    const int d = l & 3;
    const int pos_r = (d ^ ((l >> 4) & 3)) * 8;
#pragma unroll
    for (int i = 0; i < 8; ++i) {
        const int f = i * 64 + w * 16 + (l >> 2);
        const uint2 v = *(const uint2*)(lds + f * 32 + pos_r);
        const int posg = (4 * h + d) ^ (f & 7);
        *(uint2*)(xtb + (size_t)f * 32768 + (size_t)kc * 64 + posg * 8) = v;
    }

    // ownership shuffle-reduce (46 shfl vs 96): levels m=1,2,4 halve the kept
    // set (lane ends owning one sample's octet-partial), m=8,16,32 combine
    // octets (same owned sample), then per-lane term + 6-level wave tree.
    float q2[4], q4[4];
    {
        float r2[8], r4[8];
#pragma unroll
        for (int j = 0; j < 8; ++j) {
            r2[j] = __shfl_xor(p2[j], 1);
            r4[j] = __shfl_xor(p4[j], 1);
        }
        const bool up = (l & 1);
#pragma unroll
        for (int j = 0; j < 4; ++j) {
            q2[j] = up ? (p2[4 + j] + r2[4 + j]) : (p2[j] + r2[j]);
            q4[j] = up ? (p4[4 + j] + r4[4 + j]) : (p4[j] + r4[j]);
        }
    }
    float u2[2], u4[2];
    {
        float r2[4], r4[4];
#pragma unroll
        for (int j = 0; j < 4; ++j) {
            r2[j] = __shfl_xor(q2[j], 2);
            r4[j] = __shfl_xor(q4[j], 2);
        }
        const bool up = (l & 2);
#pragma unroll
        for (int j = 0; j < 2; ++j) {
            u2[j] = up ? (q2[2 + j] + r2[2 + j]) : (q2[j] + r2[j]);
            u4[j] = up ? (q4[2 + j] + r4[2 + j]) : (q4[j] + r4[j]);
        }
    }
    float s2v, s4v;
    {
        float r2a = __shfl_xor(u2[0], 4), r2b = __shfl_xor(u2[1], 4);
        float r4a = __shfl_xor(u4[0], 4), r4b = __shfl_xor(u4[1], 4);
        const bool up = (l & 4);
        s2v = up ? (u2[1] + r2b) : (u2[0] + r2a);
        s4v = up ? (u4[1] + r4b) : (u4[0] + r4a);
    }
#pragma unroll
    for (int m = 8; m < 64; m <<= 1) {
        s2v += __shfl_xor(s2v, m);
        s4v += __shfl_xor(s4v, m);
    }
    float tA = s2v * s2v - s4v;    // per owned sample, replicated x8
    float tB = s4v - 2.0f * s2v;
#pragma unroll
    for (int m = 1; m < 64; m <<= 1) {
        tA += __shfl_xor(tA, m);
        tB += __shfl_xor(tB, m);
    }
    if (l == 0) lpart4[bb * 4 + w] = make_float2(tA, tB);
}

// gram over triangle, fp8 (R8, unchanged): 640 blocks x 256 thr,
// launch_bounds(256,3) -> all co-resident (LDS 32 KB dbuf). 4 waves 2x2,
// wave = 64x64 via 4x4 of mfma_f32_16x16x32_fp8_fp8; global_load_lds dwordx4
// staging. Block map keeps XCD-locality: xcd=b&7, s=b>>3;
// kpart = xcd + 8*(s/10); tile = s%10.
__global__ __launch_bounds__(256, 3) void gram_tri_kernel(const uint8_t* __restrict__ xt,
                                                          uint16_t* __restrict__ parts) {
    __shared__ char As[2][128 * 64];
    __shared__ char Bs[2][128 * 64];

    const int b = blockIdx.x;
    const int xcd = b & 7;
    const int s = b >> 3;            // 0..79
    const int kpart = xcd + 8 * (s / NTILES);
    const int tl = s % NTILES;
    // triangle enum: (0,0)(0,1)(0,2)(0,3)(1,1)(1,2)(1,3)(2,2)(2,3)(3,3)
    const int ti = (tl < 4) ? 0 : (tl < 7) ? 1 : (tl < 9) ? 2 : 3;
    const int tj = (tl < 4) ? tl : (tl < 7) ? (tl - 3) : (tl < 9) ? (tl - 5) : 3;
    const int i0 = ti * 128;
    const int j0 = tj * 128;
    const bool diag = (ti == tj);

    const int t = threadIdx.x;
    const int l = t & 63;
    const int wv = t >> 6;
    const char* xb = (const char*)xt;

    const size_t lane_off = (size_t)(l >> 2) * 32768 + (size_t)((l & 3) * 16);
    const size_t ga = (size_t)(i0 + wv * 32) * 32768 + lane_off;
    const size_t gb = (size_t)(j0 + wv * 32) * 32768 + lane_off;

    floatx4 acc[4][4];
#pragma unroll
    for (int a = 0; a < 4; ++a)
#pragma unroll
        for (int b2 = 0; b2 < 4; ++b2) acc[a][b2] = (floatx4)0.0f;

    const int wm = (wv >> 1) * 64;
    const int wn = (wv & 1) * 64;
    const int rl = l & 15;
    const int q = l >> 4;

#define STAGE(c, buf)                                                                         \
    {                                                                                         \
        const size_t koff = (size_t)(kpart * NCHUNK + (c)) * 64;                              \
        _Pragma("unroll") for (int i = 0; i < 2; ++i) {                                       \
            __builtin_amdgcn_global_load_lds((gas_u32*)(xb + ga + (size_t)i * 16 * 32768 + koff), \
                                             (las_u32*)(As[buf] + (wv * 32 + i * 16) * 64), 16, 0, 0); \
        }                                                                                     \
        if (!diag) {                                                                          \
            _Pragma("unroll") for (int i = 0; i < 2; ++i) {                                   \
                __builtin_amdgcn_global_load_lds((gas_u32*)(xb + gb + (size_t)i * 16 * 32768 + koff), \
                                                 (las_u32*)(Bs[buf] + (wv * 32 + i * 16) * 64), 16, 0, 0); \
            }                                                                                 \
        }                                                                                     \
    }

    STAGE(0, 0);
    for (int c = 0; c < NCHUNK; ++c) {
        __syncthreads();  // drains vmcnt -> buf[c&1] image complete & visible
        if (c + 1 < NCHUNK) STAGE(c + 1, (c + 1) & 1);  // in flight during compute
        const char* Ab = As[c & 1];
        const char* Bb = diag ? Ab : Bs[c & 1];
#pragma unroll
        for (int kk = 0; kk < 2; ++kk) {
            const int qp = kk * 4 + q;  // granule within 64-sample chunk
            long af[4], bfr[4];
#pragma unroll
            for (int tm = 0; tm < 4; ++tm) {
                const int fi = wm + tm * 16 + rl;
                af[tm] = *(const long*)(Ab + fi * 64 + ((qp ^ (fi & 7)) * 8));
            }
#pragma unroll
            for (int tn = 0; tn < 4; ++tn) {
                const int fj = wn + tn * 16 + rl;
                bfr[tn] = *(const long*)(Bb + fj * 64 + ((qp ^ (fj & 7)) * 8));
            }
#pragma unroll
            for (int tm = 0; tm < 4; ++tm)
#pragma unroll
                for (int tn = 0; tn < 4; ++tn)
                    acc[tm][tn] = __builtin_amdgcn_mfma_f32_16x16x32_fp8_fp8(
                        af[tm], bfr[tn], acc[tm][tn], 0, 0, 0);
        }
    }
#undef STAGE

    // epilogue -> bf16 partial tile [kpart][tile][128][128]
    // C/D layout: col = lane&15, row = (lane>>4)*4 + reg (m89/m91)
    uint16_t* p = parts + ((size_t)kpart * NTILES + tl) * 16384;
#pragma unroll
    for (int tm = 0; tm < 4; ++tm)
#pragma unroll
        for (int tn = 0; tn < 4; ++tn)
#pragma unroll
            for (int rr = 0; rr < 4; ++rr) {
                const int gi = wm + tm * 16 + q * 4 + rr;
                const int gj = wn + tn * 16 + rl;
                p[gi * 128 + gj] = __bfloat16_as_ushort(__float2bfloat16(acc[tm][tn][rr]));
            }
}

// finalize: blocks 0..159 = (tile, strip of 8 rows); sums 64 bf16 partials,
// applies kappa transform, writes (i,j) coalesced + mirror (j,i) for off-diag
// tiles. Block 160 reduces the 4096 per-wave loss partials (x8 replication
// folded into SCALE8).
__global__ __launch_bounds__(256) void finalize_tri_kernel(const uint16_t* __restrict__ parts,
                                                           const float2* __restrict__ lpart4,
                                                           const float* __restrict__ kappa_p,
                                                           float* __restrict__ out) {
    if (blockIdx.x == 160) {
        __shared__ float sA[4], sB[4];
        const int w = threadIdx.x >> 6;
        const int l = threadIdx.x & 63;
        float a = 0.f, b = 0.f;
        for (int i = threadIdx.x; i < PREP_BLOCKS * 4; i += 256) {
            const float2 pp = lpart4[i];
            a += pp.x;
            b += pp.y;
        }
#pragma unroll
        for (int m = 1; m < 64; m <<= 1) {
            a += __shfl_xor(a, m);
            b += __shfl_xor(b, m);
        }
        if (l == 0) { sA[w] = a; sB[w] = b; }
        __syncthreads();
        if (threadIdx.x == 0) {
            const float SCALE8 = 1.4551915228366852e-11f;  // 1/(8*N*d*d)
            out[D * D] = (sA[0] + sA[1] + sA[2] + sA[3]) * SCALE8;
            out[D * D + 1] = (sB[0] + sB[1] + sB[2] + sB[3]) * SCALE8 + 0.001953125f;  // +1/d
        }
        return;
    }
    const int tl = blockIdx.x / 16;
    const int strip = blockIdx.x % 16;
    const int ti = (tl < 4) ? 0 : (tl < 7) ? 1 : (tl < 9) ? 2 : 3;
    const int tj = (tl < 4) ? tl : (tl < 7) ? (tl - 3) : (tl < 9) ? (tl - 5) : 3;

    const int tr = threadIdx.x >> 5;        // 0..7 row within strip
    const int col0 = (threadIdx.x & 31) * 4;
    const int r = strip * 8 + tr;           // 0..127 row within tile

    float s0 = 0.f, s1 = 0.f, s2 = 0.f, s3 = 0.f;
    const uint16_t* base = parts + (size_t)tl * 16384 + r * 128 + col0;
#pragma unroll 8
    for (int kp = 0; kp < KPARTS; ++kp) {
        const ushort4 v = *(const ushort4*)(base + (size_t)kp * (NTILES * 16384));
        s0 += __uint_as_float((uint32_t)v.x << 16);
        s1 += __uint_as_float((uint32_t)v.y << 16);
        s2 += __uint_as_float((uint32_t)v.z << 16);
        s3 += __uint_as_float((uint32_t)v.w << 16);
    }
    const float kappa = *kappa_p;
    const float invn = 1.0f / (float)NSAMP;
    const int gi = ti * 128 + r;
    const int gj0 = tj * 128 + col0;
    float rr[4] = {s0, s1, s2, s3};
#pragma unroll
    for (int c = 0; c < 4; ++c) {
        const float m = rr[c] * invn;
        rr[c] = (gi == gj0 + c) ? kappa * (m - 1.0f) : (1.0f - kappa) * m;
    }
    float4 o = {rr[0], rr[1], rr[2], rr[3]};
    *(float4*)(out + (size_t)gi * D + gj0) = o;
    if (ti != tj) {  // mirror
#pragma unroll
        for (int c = 0; c < 4; ++c) out[(size_t)(gj0 + c) * D + gi] = rr[c];
    }
}

// ---------- fallback path (ws too small; not expected on this harness) ----------

__global__ __launch_bounds__(256) void loss_atomic_kernel(const float* __restrict__ x,
                                                          float* __restrict__ out) {
    __shared__ float sA[4], sB[4];
    const int w = threadIdx.x >> 6;
    const int l = threadIdx.x & 63;
    const int gw = blockIdx.x * 4 + w;
    const float* base = x + (size_t)gw * 4 * D;
    float4 v[8];
#pragma unroll
    for (int r = 0; r < 4; ++r) {
        v[2 * r]     = *(const float4*)(base + (size_t)r * D + l * 4);
        v[2 * r + 1] = *(const float4*)(base + (size_t)r * D + 256 + l * 4);
    }
    float p2[4], p4[4];
#pragma unroll
    for (int r = 0; r < 4; ++r) {
        const float* f = (const float*)&v[2 * r];
        float a2 = 0.f, a4 = 0.f, e;
#pragma unroll
        for (int c = 0; c < 8; ++c) { e = f[c] * f[c]; a2 += e; a4 += e * e; }
        p2[r] = a2; p4[r] = a4;
    }
#pragma unroll
    for (int m = 1; m < 64; m <<= 1) {
#pragma unroll
        for (int r = 0; r < 4; ++r) {
            p2[r] += __shfl_xor(p2[r], m);
            p4[r] += __shfl_xor(p4[r], m);
        }
    }
    float accA = 0.f, accB = 0.f;
#pragma unroll
    for (int r = 0; r < 4; ++r) {
        accA += p2[r] * p2[r] - p4[r];
        accB += p4[r] - 2.0f * p2[r];
    }
    if (l == 0) { sA[w] = accA; sB[w] = accB; }
    __syncthreads();
    if (threadIdx.x == 0) {
        const float SCALE = 1.1641532182693481e-10f;
        atomicAdd(out + D * D, (sA[0] + sA[1] + sA[2] + sA[3]) * SCALE);
        atomicAdd(out + D * D + 1, (sB[0] + sB[1] + sB[2] + sB[3]) * SCALE);
        if (blockIdx.x == 0) atomicAdd(out + D * D + 1, 0.001953125f);
    }
}

typedef bf16x8 bf16x8_t;
__global__ __launch_bounds__(256, 2) void gram_fp32_atomic_kernel(const float* __restrict__ x,
                                                                  float* __restrict__ dst) {
    __shared__ __bf16 As[128 * 64];
    __shared__ __bf16 Bs[128 * 64];
    char* Asb = (char*)As;
    char* Bsb = (char*)Bs;
    const int kpart = blockIdx.x & (KPARTS_FB - 1);
    const int tile = blockIdx.x >> 5;
    const int i0 = (tile & 3) * 128;
    const int j0 = (tile >> 2) * 128;
    const int kbase = kpart * KC_FB;
    const int t = threadIdx.x;
    const int l = t & 63;
    const int wv = t >> 6;
    const int fq = (l & 7) + 8 * wv;
    const int ksl = l >> 3;
    const float4* x4 = (const float4*)x;
    const int aoff = (i0 >> 2) + fq;
    const int boff = (j0 >> 2) + fq;
    float4 va[8], vb[8];
#pragma unroll
    for (int r = 0; r < 4; ++r) {
        const size_t row = (size_t)(kbase + 2 * ksl + 16 * r) * 128;
        va[2 * r] = x4[row + aoff];     va[2 * r + 1] = x4[row + 128 + aoff];
        vb[2 * r] = x4[row + boff];     vb[2 * r + 1] = x4[row + 128 + boff];
    }
    floatx4 acc[4][4];
#pragma unroll
    for (int a = 0; a < 4; ++a)
#pragma unroll
        for (int b = 0; b < 4; ++b) acc[a][b] = (floatx4)0.0f;
    const int wm = (wv >> 1) * 64;
    const int wn = (wv & 1) * 64;
    const int rl = l & 15;
    const int q = l >> 4;
    for (int c = 0; c < NCHUNK_FB; ++c) {
        __syncthreads();
#pragma unroll
        for (int r = 0; r < 4; ++r) {
            const int k0 = 2 * ksl + 16 * r;
            const int g = k0 >> 3;
            const int sb = (k0 & 7) * 2;
            const float* fa0 = (const float*)&va[2 * r];
            const float* fa1 = (const float*)&va[2 * r + 1];
            const float* fb0 = (const float*)&vb[2 * r];
            const float* fb1 = (const float*)&vb[2 * r + 1];
#pragma unroll
            for (int cc = 0; cc < 4; ++cc) {
                const int f = fq * 4 + cc;
                const int off = f * 128 + ((g ^ (f & 7)) * 16) + sb;
                unsigned int pa = (unsigned int)__bfloat16_as_ushort(__float2bfloat16(fa0[cc])) |
                                  ((unsigned int)__bfloat16_as_ushort(__float2bfloat16(fa1[cc])) << 16);
                unsigned int pb = (unsigned int)__bfloat16_as_ushort(__float2bfloat16(fb0[cc])) |
                                  ((unsigned int)__bfloat16_as_ushort(__float2bfloat16(fb1[cc])) << 16);
                *(unsigned int*)(Asb + off) = pa;
                *(unsigned int*)(Bsb + off) = pb;
            }
        }
        if (c + 1 < NCHUNK_FB) {
            const int kb = kbase + (c + 1) * BK_FB;
#pragma unroll
            for (int r = 0; r < 4; ++r) {
                const size_t row = (size_t)(kb + 2 * ksl + 16 * r) * 128;
                va[2 * r] = x4[row + aoff];     va[2 * r + 1] = x4[row + 128 + aoff];
                vb[2 * r] = x4[row + boff];     vb[2 * r + 1] = x4[row + 128 + boff];
            }
        }
        __syncthreads();
#pragma unroll
        for (int kk = 0; kk < 2; ++kk) {
            const int qp = kk * 4 + q;
            bf16x8_t af[4], bfr[4];
#pragma unroll
            for (int tm = 0; tm < 4; ++tm) {
                const int fi = wm + tm * 16 + rl;
                af[tm] = *(const bf16x8_t*)(Asb + fi * 128 + ((qp ^ (fi & 7)) * 16));
            }
#pragma unroll
            for (int tn = 0; tn < 4; ++tn) {
                const int fj = wn + tn * 16 + rl;
                bfr[tn] = *(const bf16x8_t*)(Bsb + fj * 128 + ((qp ^ (fj & 7)) * 16));
            }
#pragma unroll
            for (int tm = 0; tm < 4; ++tm)
#pragma unroll
                for (int tn = 0; tn < 4; ++tn)
                    acc[tm][tn] = __builtin_amdgcn_mfma_f32_16x16x32_bf16(
                        af[tm], bfr[tn], acc[tm][tn], 0, 0, 0);
        }
    }
#pragma unroll
    for (int tm = 0; tm < 4; ++tm)
#pragma unroll
        for (int tn = 0; tn < 4; ++tn)
#pragma unroll
            for (int rr = 0; rr < 4; ++rr) {
                const int gi = i0 + wm + tm * 16 + q * 4 + rr;
                const int gj = j0 + wn + tn * 16 + rl;
                atomicAdd(dst + (size_t)gi * D + gj, acc[tm][tn][rr]);
            }
}

__global__ __launch_bounds__(256) void finalize1_kernel(const float* __restrict__ src,
                                                        const float* __restrict__ kappa_p,
                                                        float* __restrict__ out) {
    const int base = (blockIdx.x * 256 + threadIdx.x) * 4;
    float4 s = *(const float4*)(src + base);
    const float kappa = *kappa_p;
    const float invn = 1.0f / (float)NSAMP;
    const int i = base >> 9;
    const int j = base & (D - 1);
    float r[4] = {s.x, s.y, s.z, s.w};
#pragma unroll
    for (int cpt = 0; cpt < 4; ++cpt) {
        const float m = r[cpt] * invn;
        r[cpt] = (i == j + cpt) ? kappa * (m - 1.0f) : (1.0f - kappa) * m;
    }
    float4 o = {r[0], r[1], r[2], r[3]};
    *(float4*)(out + base) = o;
}

extern "C" void kernel_launch(void* const* d_in, const int* in_sizes, int n_in,
                              void* d_out, int out_size, void* d_ws, size_t ws_size,
                              hipStream_t stream) {
    const float* x = (const float*)d_in[0];
    const float* kappa = (const float*)d_in[1];
    float* out = (float*)d_out;

    const size_t xt_bytes = (size_t)D * NSAMP;                                     // 16 MB
    const size_t parts_bytes = (size_t)KPARTS * NTILES * 16384 * sizeof(uint16_t); // 20 MB
    const size_t lpart_bytes = (size_t)PREP_BLOCKS * 4 * sizeof(float2);           // 32 KB

    if (ws_size >= xt_bytes + parts_bytes + lpart_bytes) {
        uint8_t* xt = (uint8_t*)d_ws;
        uint16_t* parts = (uint16_t*)((char*)d_ws + xt_bytes);
        float2* lpart4 = (float2*)((char*)d_ws + xt_bytes + parts_bytes);
        prep_kernel<<<PREP_BLOCKS, 256, 0, stream>>>(x, xt, lpart4);
        gram_tri_kernel<<<8 * NTILES * (KPARTS / 8), 256, 0, stream>>>(xt, parts);
        finalize_tri_kernel<<<161, 256, 0, stream>>>(parts, lpart4, kappa, out);
    } else {
        zero_kernel<<<(out_size + 1023) / 1024, 1024, 0, stream>>>(out, out_size);
        loss_atomic_kernel<<<2048, 256, 0, stream>>>(x, out);
        gram_fp32_atomic_kernel<<<16 * KPARTS_FB, 256, 0, stream>>>(x, out);
        finalize1_kernel<<<(D * D / 4) / 256, 256, 0, stream>>>(out, kappa, out);
    }
}